// Round 1
// baseline (2199.506 us; speedup 1.0000x reference)
//
#include <hip/hip_runtime.h>
#include <hip/hip_bf16.h>
#include <cstddef>

#define H 1280
#define RB 8
#define BS 160
#define HEADS 20
#define HD 64
#define BATCH 16
#define SEQ 1024
#define SE 77
#define CENC 768
#define CONSTR 1.28f
#define EPS_N 1e-8f

// workspace offsets (in floats)
#define QS_OFF   0              // 3*8*160*160 = 614400
#define PA_OFF   614400
#define PB_OFF   1228800
#define WQF_OFF  1843200        // 1280*1280 = 1638400
#define WKF_OFF  3481600        // 768*1280 = 983040
#define WVF_OFF  4464640        // 768*1280 = 983040
#define QBUF_OFF 5447680        // 16384*1280 = 20971520
#define KBUF_OFF 26419200       // 1232*1280 = 1576960
#define VBUF_OFF 27996160       // 1232*1280 = 1576960

// ---------------------------------------------------------------------------
// 1) Q = W - W^T, scaled by (min(||Q||_F, c)+eps)/(||Q||_F+eps).  One wg per W.
// ---------------------------------------------------------------------------
__global__ __launch_bounds__(1024) void skew_kernel(
    const float* __restrict__ W0, const float* __restrict__ W1,
    const float* __restrict__ W2, float* __restrict__ Qs) {
  int w = blockIdx.x;
  const float* W = (w == 0) ? W0 : ((w == 1) ? W1 : W2);
  float* Qout = Qs + (size_t)w * RB * BS * BS;
  __shared__ float red[1024];
  __shared__ float s_scale;
  float local = 0.f;
  for (int idx = threadIdx.x; idx < RB * BS * BS; idx += 1024) {
    int r = idx / (BS * BS);
    int rem = idx % (BS * BS);
    int i = rem / BS, j = rem % BS;
    float q = W[idx] - W[r * BS * BS + j * BS + i];
    local += q * q;
  }
  red[threadIdx.x] = local;
  __syncthreads();
  for (int s = 512; s > 0; s >>= 1) {
    if (threadIdx.x < (unsigned)s) red[threadIdx.x] += red[threadIdx.x + s];
    __syncthreads();
  }
  if (threadIdx.x == 0) {
    float n = sqrtf(red[0]);
    s_scale = (fminf(n, CONSTR) + EPS_N) / (n + EPS_N);
  }
  __syncthreads();
  float sc = s_scale;
  for (int idx = threadIdx.x; idx < RB * BS * BS; idx += 1024) {
    int r = idx / (BS * BS);
    int rem = idx % (BS * BS);
    int i = rem / BS, j = rem % BS;
    Qout[idx] = (W[idx] - W[r * BS * BS + j * BS + i]) * sc;
  }
}

// ---------------------------------------------------------------------------
// 2) Horner step: Pout = Q @ (Pin + I) per 160x160 block.
//    grid = 24 blocks * 25 (5x5 strip) tiles; each wg -> 32x32 output tile.
// ---------------------------------------------------------------------------
__global__ __launch_bounds__(256) void horner_kernel(
    const float* __restrict__ Qs, const float* __restrict__ Pin,
    float* __restrict__ Pout) {
  int wr = blockIdx.x / 25;  // 0..23 = w*8 + r
  int st = blockIdx.x % 25;
  int is = st / 5, js = st % 5;
  const float* Ag = Qs + (size_t)wr * BS * BS;
  const float* Bg = Pin + (size_t)wr * BS * BS;
  float* Og = Pout + (size_t)wr * BS * BS;
  __shared__ float As[32 * 160];
  __shared__ float Bsh[160 * 32];
  for (int idx = threadIdx.x; idx < 32 * 160; idx += 256) {
    int rr = idx / 160, c = idx % 160;
    As[idx] = Ag[(is * 32 + rr) * 160 + c];
    int k = idx / 32, jj = idx % 32;
    int jglob = js * 32 + jj;
    float v = Bg[k * 160 + jglob];
    if (k == jglob) v += 1.f;
    Bsh[k * 32 + jj] = v;
  }
  __syncthreads();
  int ti = threadIdx.x / 32, tj = threadIdx.x % 32;
  float a0 = 0.f, a1 = 0.f, a2 = 0.f, a3 = 0.f;
  for (int k = 0; k < 160; ++k) {
    float b = Bsh[k * 32 + tj];
    a0 += As[(ti)*160 + k] * b;
    a1 += As[(ti + 8) * 160 + k] * b;
    a2 += As[(ti + 16) * 160 + k] * b;
    a3 += As[(ti + 24) * 160 + k] * b;
  }
  Og[(is * 32 + ti) * 160 + js * 32 + tj] = a0;
  Og[(is * 32 + ti + 8) * 160 + js * 32 + tj] = a1;
  Og[(is * 32 + ti + 16) * 160 + js * 32 + tj] = a2;
  Og[(is * 32 + ti + 24) * 160 + js * 32 + tj] = a3;
}

// ---------------------------------------------------------------------------
// 3) Fold rotation into weights: W'[:,blk r] = W[:,blk r] @ (I + 2P_r)
//    grid = (r=8, rowtile, w=3); 64 rows per wg.
// ---------------------------------------------------------------------------
__global__ __launch_bounds__(256) void fold_kernel(
    const float* __restrict__ Wq, const float* __restrict__ Wk,
    const float* __restrict__ Wv, const float* __restrict__ P,
    float* __restrict__ WqF, float* __restrict__ WkF,
    float* __restrict__ WvF) {
  int r = blockIdx.x;
  int rt = blockIdx.y;
  int w = blockIdx.z;
  int rows = (w == 0) ? H : CENC;
  if (rt * 64 >= rows) return;
  const float* Wg = (w == 0) ? Wq : ((w == 1) ? Wk : Wv);
  float* Og = (w == 0) ? WqF : ((w == 1) ? WkF : WvF);
  const float* Pg = P + (size_t)(w * RB + r) * BS * BS;
  __shared__ float As[64 * 160];
  __shared__ float Ps[160 * 32];
  for (int idx = threadIdx.x; idx < 64 * 160; idx += 256) {
    int rr = idx / 160, c = idx % 160;
    As[idx] = Wg[(size_t)(rt * 64 + rr) * H + r * 160 + c];
  }
  int ti = threadIdx.x / 32, tc = threadIdx.x % 32;
  for (int strip = 0; strip < 5; ++strip) {
    __syncthreads();
    for (int idx = threadIdx.x; idx < 160 * 32; idx += 256) {
      int d = idx / 32, cc = idx % 32;
      Ps[idx] = Pg[d * 160 + strip * 32 + cc];
    }
    __syncthreads();
    float acc[8];
#pragma unroll
    for (int m = 0; m < 8; m++) acc[m] = 0.f;
    for (int d = 0; d < 160; ++d) {
      float p = Ps[d * 32 + tc];
#pragma unroll
      for (int m = 0; m < 8; m++) acc[m] += As[(ti * 8 + m) * 160 + d] * p;
    }
#pragma unroll
    for (int m = 0; m < 8; m++) {
      int row = ti * 8 + m;
      Og[(size_t)(rt * 64 + row) * H + r * 160 + strip * 32 + tc] =
          As[row * 160 + strip * 32 + tc] + 2.f * acc[m];
    }
  }
}

// ---------------------------------------------------------------------------
// 4) fp32 GEMM: C[M,N] = A[M,K] @ B[K,N] (+bias). BM=128 BN=64 BK=32.
// ---------------------------------------------------------------------------
__global__ __launch_bounds__(256) void gemm_kernel(
    const float* __restrict__ A, const float* __restrict__ Bm,
    float* __restrict__ Cm, int M, int N, int K,
    const float* __restrict__ bias) {
  const int BM = 128, BN = 64, BK = 32;
  int m0 = blockIdx.x * BM;
  int n0 = blockIdx.y * BN;
  __shared__ float As[BK][132];  // transposed A tile, padded stride
  __shared__ float Bs[BK][BN];
  int t = threadIdx.x;
  int ti = t / 16, tn = t % 16;
  float acc[8][4];
#pragma unroll
  for (int i = 0; i < 8; i++)
#pragma unroll
    for (int j = 0; j < 4; j++) acc[i][j] = 0.f;
  int a_kq = t % 8;
  int a_row = t / 8;  // 0..31
  int b_kr = t / 16;  // 0..15
  int b_col = (t % 16) * 4;
  for (int k0 = 0; k0 < K; k0 += BK) {
    __syncthreads();
#pragma unroll
    for (int bb = 0; bb < 4; ++bb) {
      int row = a_row + bb * 32;
      float4 v;
      if (m0 + row < M)
        v = *(const float4*)&A[(size_t)(m0 + row) * K + k0 + a_kq * 4];
      else
        v = make_float4(0.f, 0.f, 0.f, 0.f);
      As[a_kq * 4 + 0][row] = v.x;
      As[a_kq * 4 + 1][row] = v.y;
      As[a_kq * 4 + 2][row] = v.z;
      As[a_kq * 4 + 3][row] = v.w;
    }
#pragma unroll
    for (int bb = 0; bb < 2; ++bb) {
      int kr = b_kr + bb * 16;
      *(float4*)&Bs[kr][b_col] =
          *(const float4*)&Bm[(size_t)(k0 + kr) * N + n0 + b_col];
    }
    __syncthreads();
#pragma unroll
    for (int kk = 0; kk < BK; ++kk) {
      float4 a0 = *(const float4*)&As[kk][ti * 8];
      float4 a1 = *(const float4*)&As[kk][ti * 8 + 4];
      float4 b = *(const float4*)&Bs[kk][tn * 4];
      float av[8] = {a0.x, a0.y, a0.z, a0.w, a1.x, a1.y, a1.z, a1.w};
      float bv[4] = {b.x, b.y, b.z, b.w};
#pragma unroll
      for (int i = 0; i < 8; i++)
#pragma unroll
        for (int j = 0; j < 4; j++) acc[i][j] += av[i] * bv[j];
    }
  }
  float4 bv4 = make_float4(0.f, 0.f, 0.f, 0.f);
  if (bias) bv4 = *(const float4*)&bias[n0 + tn * 4];
#pragma unroll
  for (int i = 0; i < 8; i++) {
    int row = m0 + ti * 8 + i;
    if (row < M) {
      float4 o;
      o.x = acc[i][0] + bv4.x;
      o.y = acc[i][1] + bv4.y;
      o.z = acc[i][2] + bv4.z;
      o.w = acc[i][3] + bv4.w;
      *(float4*)&Cm[(size_t)row * N + n0 + tn * 4] = o;
    }
  }
}

// ---------------------------------------------------------------------------
// 5) Attention: one wg per (b, h, 64-query tile). K/V/S in LDS. In-place out
//    into qbuf.
// ---------------------------------------------------------------------------
__global__ __launch_bounds__(256) void attn_kernel(
    float* __restrict__ qbuf, const float* __restrict__ kbuf,
    const float* __restrict__ vbuf) {
  int bid = blockIdx.x;
  int qt = bid % 16;
  int h = (bid / 16) % HEADS;
  int b = bid / (16 * HEADS);
  int s0 = qt * 64;
  __shared__ float Ks[SE * 64];
  __shared__ float Vs[SE * 64];
  __shared__ float Ss[SE * 64];
  int t = threadIdx.x;
  for (int idx = t; idx < SE * 64; idx += 256) {
    int j = idx / 64, d = idx % 64;
    Ks[idx] = kbuf[(size_t)(b * SE + j) * H + h * 64 + d];
    Vs[idx] = vbuf[(size_t)(b * SE + j) * H + h * 64 + d];
  }
  __syncthreads();
  int qi = t % 64;
  int grp = t / 64;
  const float* qrow = qbuf + (size_t)(b * SEQ + s0 + qi) * H + h * 64;
  float4 qr[16];
#pragma unroll
  for (int dd = 0; dd < 16; ++dd) qr[dd] = *(const float4*)&qrow[dd * 4];
  for (int j = grp; j < SE; j += 4) {
    float acc = 0.f;
#pragma unroll
    for (int dd = 0; dd < 16; ++dd) {
      float4 k4 = *(const float4*)&Ks[j * 64 + dd * 4];
      acc += qr[dd].x * k4.x + qr[dd].y * k4.y + qr[dd].z * k4.z +
             qr[dd].w * k4.w;
    }
    Ss[j * 64 + qi] = acc * 0.125f;  // 1/sqrt(64)
  }
  __syncthreads();
  if (t < 64) {
    float m = -1e30f;
    for (int j = 0; j < SE; ++j) m = fmaxf(m, Ss[j * 64 + t]);
    float sum = 0.f;
    for (int j = 0; j < SE; ++j) {
      float e = __expf(Ss[j * 64 + t] - m);
      Ss[j * 64 + t] = e;
      sum += e;
    }
    float inv = 1.f / sum;
    for (int j = 0; j < SE; ++j) Ss[j * 64 + t] *= inv;
  }
  __syncthreads();
  int d = t % 64;
  int qg = t / 64;
  float acc[16];
#pragma unroll
  for (int m = 0; m < 16; m++) acc[m] = 0.f;
  for (int j = 0; j < SE; ++j) {
    float v = Vs[j * 64 + d];
#pragma unroll
    for (int m = 0; m < 16; m++) acc[m] += Ss[j * 64 + qg * 16 + m] * v;
  }
#pragma unroll
  for (int m = 0; m < 16; m++) {
    qbuf[(size_t)(b * SEQ + s0 + qg * 16 + m) * H + h * 64 + d] = acc[m];
  }
}

// ---------------------------------------------------------------------------
extern "C" void kernel_launch(void* const* d_in, const int* in_sizes, int n_in,
                              void* d_out, int out_size, void* d_ws,
                              size_t ws_size, hipStream_t stream) {
  const float* hidden = (const float*)d_in[0];
  const float* enc = (const float*)d_in[1];
  const float* W_Q = (const float*)d_in[2];
  const float* W_K = (const float*)d_in[3];
  const float* W_V = (const float*)d_in[4];
  const float* Wq = (const float*)d_in[5];
  const float* Wk = (const float*)d_in[6];
  const float* Wv = (const float*)d_in[7];
  const float* Wo = (const float*)d_in[8];
  const float* bo = (const float*)d_in[9];
  float* out = (float*)d_out;
  float* ws = (float*)d_ws;

  float* Qs = ws + QS_OFF;
  float* Pa = ws + PA_OFF;
  float* Pb = ws + PB_OFF;
  float* WqF = ws + WQF_OFF;
  float* WkF = ws + WKF_OFF;
  float* WvF = ws + WVF_OFF;
  float* qbuf = ws + QBUF_OFF;
  float* kbuf = ws + KBUF_OFF;
  float* vbuf = ws + VBUF_OFF;

  // Cayley via Neumann series folded into the projection weights
  skew_kernel<<<3, 1024, 0, stream>>>(W_Q, W_K, W_V, Qs);
  horner_kernel<<<600, 256, 0, stream>>>(Qs, Qs, Pa);  // P2
  horner_kernel<<<600, 256, 0, stream>>>(Qs, Pa, Pb);  // P3
  horner_kernel<<<600, 256, 0, stream>>>(Qs, Pb, Pa);  // P4
  horner_kernel<<<600, 256, 0, stream>>>(Qs, Pa, Pb);  // P5
  horner_kernel<<<600, 256, 0, stream>>>(Qs, Pb, Pa);  // P6 = sum Q..Q^6
  fold_kernel<<<dim3(8, 20, 3), 256, 0, stream>>>(Wq, Wk, Wv, Pa, WqF, WkF,
                                                  WvF);

  // projections
  gemm_kernel<<<dim3(128, 20), 256, 0, stream>>>(hidden, WqF, qbuf,
                                                 BATCH * SEQ, H, H, nullptr);
  gemm_kernel<<<dim3(10, 20), 256, 0, stream>>>(enc, WkF, kbuf, BATCH * SE, H,
                                                CENC, nullptr);
  gemm_kernel<<<dim3(10, 20), 256, 0, stream>>>(enc, WvF, vbuf, BATCH * SE, H,
                                                CENC, nullptr);

  // attention (in-place into qbuf)
  attn_kernel<<<BATCH * HEADS * (SEQ / 64), 256, 0, stream>>>(qbuf, kbuf,
                                                              vbuf);

  // output projection + bias
  gemm_kernel<<<dim3(128, 20), 256, 0, stream>>>(qbuf, Wo, out, BATCH * SEQ, H,
                                                 H, bo);
}

// Round 2
// 1236.591 us; speedup vs baseline: 1.7787x; 1.7787x over previous
//
#include <hip/hip_runtime.h>
#include <cstddef>
#include <cstdint>

#define H 1280
#define RB 8
#define BS 160
#define HEADS 20
#define HD 64
#define BATCH 16
#define SEQ 1024
#define SE 77
#define CENC 768
#define CONSTR 1.28f
#define EPS_N 1e-8f

// workspace offsets (in floats)
#define QS_OFF    0u           // 614400
#define PA_OFF    614400u
#define PB_OFF    1228800u
#define WQF_OFF   1843200u     // 1638400
#define WKF_OFF   3481600u     // 983040
#define WVF_OFF   4464640u     // 983040
#define QBUF_OFF  5447680u     // 20971520
#define KBUF_OFF  26419200u    // 1576960
#define VBUF_OFF  27996160u    // 1576960
#define HIDH_OFF  29573120u    // 10485760 floats (20971520 shorts)
#define HIDL_OFF  40058880u    // 10485760
#define ENCH_OFF  50544640u    // 473088
#define ENCL_OFF  51017728u    // 473088
#define WQTH_OFF  51490816u    // 819200
#define WQTL_OFF  52310016u    // 819200
#define WKTH_OFF  53129216u    // 491520
#define WKTL_OFF  53620736u    // 491520
#define WVTH_OFF  54112256u    // 491520
#define WVTL_OFF  54603776u    // 491520
#define WOTH_OFF  55095296u    // 819200
#define WOTL_OFF  55914496u    // 819200
// AO (attn output, bf16 hi/lo) overlays HIDH/HIDL (dead after q GEMM)

typedef __attribute__((ext_vector_type(8))) short short8v;
typedef __attribute__((ext_vector_type(4))) float f32x4;

__device__ __forceinline__ short f2bf(float x) {
  unsigned u = __float_as_uint(x);
  unsigned r = (u + 0x7fffu + ((u >> 16) & 1u)) >> 16;
  return (short)r;
}
__device__ __forceinline__ float bf2f(short h) {
  return __uint_as_float(((unsigned)(unsigned short)h) << 16);
}

// ---------------------------------------------------------------------------
// 1) Q = W - W^T, scaled by (min(||Q||_F, c)+eps)/(||Q||_F+eps).  One wg per W.
// ---------------------------------------------------------------------------
__global__ __launch_bounds__(1024) void skew_kernel(
    const float* __restrict__ W0, const float* __restrict__ W1,
    const float* __restrict__ W2, float* __restrict__ Qs) {
  int w = blockIdx.x;
  const float* W = (w == 0) ? W0 : ((w == 1) ? W1 : W2);
  float* Qout = Qs + (size_t)w * RB * BS * BS;
  __shared__ float red[1024];
  __shared__ float s_scale;
  float local = 0.f;
  for (int idx = threadIdx.x; idx < RB * BS * BS; idx += 1024) {
    int r = idx / (BS * BS);
    int rem = idx % (BS * BS);
    int i = rem / BS, j = rem % BS;
    float q = W[idx] - W[r * BS * BS + j * BS + i];
    local += q * q;
  }
  red[threadIdx.x] = local;
  __syncthreads();
  for (int s = 512; s > 0; s >>= 1) {
    if (threadIdx.x < (unsigned)s) red[threadIdx.x] += red[threadIdx.x + s];
    __syncthreads();
  }
  if (threadIdx.x == 0) {
    float n = sqrtf(red[0]);
    s_scale = (fminf(n, CONSTR) + EPS_N) / (n + EPS_N);
  }
  __syncthreads();
  float sc = s_scale;
  for (int idx = threadIdx.x; idx < RB * BS * BS; idx += 1024) {
    int r = idx / (BS * BS);
    int rem = idx % (BS * BS);
    int i = rem / BS, j = rem % BS;
    Qout[idx] = (W[idx] - W[r * BS * BS + j * BS + i]) * sc;
  }
}

// ---------------------------------------------------------------------------
// 2) Horner step: Pout = Q @ (Pin + I) per 160x160 block.
// ---------------------------------------------------------------------------
__global__ __launch_bounds__(256) void horner_kernel(
    const float* __restrict__ Qs, const float* __restrict__ Pin,
    float* __restrict__ Pout) {
  int wr = blockIdx.x / 25;
  int st = blockIdx.x % 25;
  int is = st / 5, js = st % 5;
  const float* Ag = Qs + (size_t)wr * BS * BS;
  const float* Bg = Pin + (size_t)wr * BS * BS;
  float* Og = Pout + (size_t)wr * BS * BS;
  __shared__ float As[32 * 160];
  __shared__ float Bsh[160 * 32];
  for (int idx = threadIdx.x; idx < 32 * 160; idx += 256) {
    int rr = idx / 160, c = idx % 160;
    As[idx] = Ag[(is * 32 + rr) * 160 + c];
    int k = idx / 32, jj = idx % 32;
    int jglob = js * 32 + jj;
    float v = Bg[k * 160 + jglob];
    if (k == jglob) v += 1.f;
    Bsh[k * 32 + jj] = v;
  }
  __syncthreads();
  int ti = threadIdx.x / 32, tj = threadIdx.x % 32;
  float a0 = 0.f, a1 = 0.f, a2 = 0.f, a3 = 0.f;
  for (int k = 0; k < 160; ++k) {
    float b = Bsh[k * 32 + tj];
    a0 += As[(ti)*160 + k] * b;
    a1 += As[(ti + 8) * 160 + k] * b;
    a2 += As[(ti + 16) * 160 + k] * b;
    a3 += As[(ti + 24) * 160 + k] * b;
  }
  Og[(is * 32 + ti) * 160 + js * 32 + tj] = a0;
  Og[(is * 32 + ti + 8) * 160 + js * 32 + tj] = a1;
  Og[(is * 32 + ti + 16) * 160 + js * 32 + tj] = a2;
  Og[(is * 32 + ti + 24) * 160 + js * 32 + tj] = a3;
}

// ---------------------------------------------------------------------------
// 3) Fold rotation into weights: W'[:,blk r] = W[:,blk r] @ (I + 2P_r)
// ---------------------------------------------------------------------------
__global__ __launch_bounds__(256) void fold_kernel(
    const float* __restrict__ Wq, const float* __restrict__ Wk,
    const float* __restrict__ Wv, const float* __restrict__ P,
    float* __restrict__ WqF, float* __restrict__ WkF,
    float* __restrict__ WvF) {
  int r = blockIdx.x;
  int rt = blockIdx.y;
  int w = blockIdx.z;
  int rows = (w == 0) ? H : CENC;
  if (rt * 64 >= rows) return;
  const float* Wg = (w == 0) ? Wq : ((w == 1) ? Wk : Wv);
  float* Og = (w == 0) ? WqF : ((w == 1) ? WkF : WvF);
  const float* Pg = P + (size_t)(w * RB + r) * BS * BS;
  __shared__ float As[64 * 160];
  __shared__ float Ps[160 * 32];
  for (int idx = threadIdx.x; idx < 64 * 160; idx += 256) {
    int rr = idx / 160, c = idx % 160;
    As[idx] = Wg[(size_t)(rt * 64 + rr) * H + r * 160 + c];
  }
  int ti = threadIdx.x / 32, tc = threadIdx.x % 32;
  for (int strip = 0; strip < 5; ++strip) {
    __syncthreads();
    for (int idx = threadIdx.x; idx < 160 * 32; idx += 256) {
      int d = idx / 32, cc = idx % 32;
      Ps[idx] = Pg[d * 160 + strip * 32 + cc];
    }
    __syncthreads();
    float acc[8];
#pragma unroll
    for (int m = 0; m < 8; m++) acc[m] = 0.f;
    for (int d = 0; d < 160; ++d) {
      float p = Ps[d * 32 + tc];
#pragma unroll
      for (int m = 0; m < 8; m++) acc[m] += As[(ti * 8 + m) * 160 + d] * p;
    }
#pragma unroll
    for (int m = 0; m < 8; m++) {
      int row = ti * 8 + m;
      Og[(size_t)(rt * 64 + row) * H + r * 160 + strip * 32 + tc] =
          As[row * 160 + strip * 32 + tc] + 2.f * acc[m];
    }
  }
}

// ---------------------------------------------------------------------------
// 4a) elementwise fp32 -> bf16 hi/lo split
// ---------------------------------------------------------------------------
__global__ __launch_bounds__(256) void split_kernel(
    const float* __restrict__ in, short* __restrict__ hi,
    short* __restrict__ lo, int n4) {
  int stride = gridDim.x * 256;
  for (int idx = blockIdx.x * 256 + threadIdx.x; idx < n4; idx += stride) {
    float4 v = ((const float4*)in)[idx];
    short h0 = f2bf(v.x), h1 = f2bf(v.y), h2 = f2bf(v.z), h3 = f2bf(v.w);
    short l0 = f2bf(v.x - bf2f(h0));
    short l1 = f2bf(v.y - bf2f(h1));
    short l2 = f2bf(v.z - bf2f(h2));
    short l3 = f2bf(v.w - bf2f(h3));
    ((short4*)hi)[idx] = make_short4(h0, h1, h2, h3);
    ((short4*)lo)[idx] = make_short4(l0, l1, l2, l3);
  }
}

// ---------------------------------------------------------------------------
// 4b) transpose + split: in [Kdim][Ndim] fp32 -> out [Ndim][Kdim] bf16 hi/lo
// ---------------------------------------------------------------------------
__global__ __launch_bounds__(256) void tsplit_kernel(
    const float* __restrict__ in, short* __restrict__ hi,
    short* __restrict__ lo, int Kdim, int Ndim) {
  __shared__ float tile[32][33];
  int kb = blockIdx.x * 32, nb = blockIdx.y * 32;
  int tx = threadIdx.x & 31, ty = threadIdx.x >> 5;  // 8 rows/pass
  for (int r = ty; r < 32; r += 8)
    tile[r][tx] = in[(size_t)(kb + r) * Ndim + nb + tx];
  __syncthreads();
  for (int r = ty; r < 32; r += 8) {
    float x = tile[tx][r];
    short h = f2bf(x);
    short l = f2bf(x - bf2f(h));
    size_t o = (size_t)(nb + r) * Kdim + kb + tx;
    hi[o] = h;
    lo[o] = l;
  }
}

// ---------------------------------------------------------------------------
// 5) split bf16 MFMA GEMM: C[M,N] = A[M,K] @ B[N,K]^T  (B stored transposed)
//    A given as hi/lo bf16, B as hi/lo bf16. 128x128 tile, BK=32, 4 waves.
// ---------------------------------------------------------------------------
__global__ __launch_bounds__(256, 2) void gemm_mfma(
    const short* __restrict__ Ah, const short* __restrict__ Al,
    const short* __restrict__ Bh, const short* __restrict__ Bl,
    float* __restrict__ C, int M, int N, int K,
    const float* __restrict__ bias) {
  __shared__ __align__(16) short As[2][128][40];
  __shared__ __align__(16) short Bs[2][128][40];
  int t = threadIdx.x;
  int m0 = blockIdx.x * 128, n0 = blockIdx.y * 128;
  int wv = t >> 6, l = t & 63;
  int wm = (wv >> 1) * 64, wn = (wv & 1) * 64;
  f32x4 acc[4][4];
#pragma unroll
  for (int m = 0; m < 4; m++)
#pragma unroll
    for (int n = 0; n < 4; n++) acc[m][n] = (f32x4){0.f, 0.f, 0.f, 0.f};

  int lr = l & 15;
  int kq = (l >> 4) * 8;

  for (int k0 = 0; k0 < K; k0 += 32) {
    __syncthreads();
#pragma unroll
    for (int i = 0; i < 2; ++i) {
      int idx = t + i * 256;
      int row = idx >> 2, c = idx & 3;
      int ar = m0 + row;
      if (ar >= M) ar = M - 1;
      size_t ga = (size_t)ar * K + k0 + c * 8;
      size_t gb = (size_t)(n0 + row) * K + k0 + c * 8;
      *(short8v*)&As[0][row][c * 8] = *(const short8v*)&Ah[ga];
      *(short8v*)&As[1][row][c * 8] = *(const short8v*)&Al[ga];
      *(short8v*)&Bs[0][row][c * 8] = *(const short8v*)&Bh[gb];
      *(short8v*)&Bs[1][row][c * 8] = *(const short8v*)&Bl[gb];
    }
    __syncthreads();
    short8v ah[4], al[4], bh[4], bl[4];
#pragma unroll
    for (int m = 0; m < 4; ++m) {
      ah[m] = *(const short8v*)&As[0][wm + m * 16 + lr][kq];
      al[m] = *(const short8v*)&As[1][wm + m * 16 + lr][kq];
    }
#pragma unroll
    for (int n = 0; n < 4; ++n) {
      bh[n] = *(const short8v*)&Bs[0][wn + n * 16 + lr][kq];
      bl[n] = *(const short8v*)&Bs[1][wn + n * 16 + lr][kq];
    }
#pragma unroll
    for (int m = 0; m < 4; ++m)
#pragma unroll
      for (int n = 0; n < 4; ++n) {
        acc[m][n] = __builtin_amdgcn_mfma_f32_16x16x32_bf16(ah[m], bh[n],
                                                            acc[m][n], 0, 0, 0);
        acc[m][n] = __builtin_amdgcn_mfma_f32_16x16x32_bf16(ah[m], bl[n],
                                                            acc[m][n], 0, 0, 0);
        acc[m][n] = __builtin_amdgcn_mfma_f32_16x16x32_bf16(al[m], bh[n],
                                                            acc[m][n], 0, 0, 0);
      }
  }

  int rbase = m0 + wm + (l >> 4) * 4;
#pragma unroll
  for (int n = 0; n < 4; ++n) {
    int col = n0 + wn + n * 16 + lr;
    float bv = bias ? bias[col] : 0.f;
#pragma unroll
    for (int m = 0; m < 4; ++m) {
#pragma unroll
      for (int r = 0; r < 4; ++r) {
        int row = rbase + m * 16 + r;
        if (row < M) C[(size_t)row * N + col] = acc[m][n][r] + bv;
      }
    }
  }
}

// ---------------------------------------------------------------------------
// 6) Attention: one wg per (b, h, 64-query tile). Writes bf16 hi/lo output.
// ---------------------------------------------------------------------------
__global__ __launch_bounds__(256) void attn_kernel(
    const float* __restrict__ qbuf, const float* __restrict__ kbuf,
    const float* __restrict__ vbuf, short* __restrict__ aoh,
    short* __restrict__ aol) {
  int bid = blockIdx.x;
  int qt = bid % 16;
  int h = (bid / 16) % HEADS;
  int b = bid / (16 * HEADS);
  int s0 = qt * 64;
  __shared__ float Ks[SE * 64];
  __shared__ float Vs[SE * 64];
  __shared__ float Ss[SE * 64];
  int t = threadIdx.x;
  for (int idx = t; idx < SE * 64; idx += 256) {
    int j = idx / 64, d = idx % 64;
    Ks[idx] = kbuf[(size_t)(b * SE + j) * H + h * 64 + d];
    Vs[idx] = vbuf[(size_t)(b * SE + j) * H + h * 64 + d];
  }
  __syncthreads();
  int qi = t % 64;
  int grp = t / 64;
  const float* qrow = qbuf + (size_t)(b * SEQ + s0 + qi) * H + h * 64;
  float4 qr[16];
#pragma unroll
  for (int dd = 0; dd < 16; ++dd) qr[dd] = *(const float4*)&qrow[dd * 4];
  for (int j = grp; j < SE; j += 4) {
    float acc = 0.f;
#pragma unroll
    for (int dd = 0; dd < 16; ++dd) {
      float4 k4 = *(const float4*)&Ks[j * 64 + dd * 4];
      acc += qr[dd].x * k4.x + qr[dd].y * k4.y + qr[dd].z * k4.z +
             qr[dd].w * k4.w;
    }
    Ss[j * 64 + qi] = acc * 0.125f;
  }
  __syncthreads();
  if (t < 64) {
    float m = -1e30f;
    for (int j = 0; j < SE; ++j) m = fmaxf(m, Ss[j * 64 + t]);
    float sum = 0.f;
    for (int j = 0; j < SE; ++j) {
      float e = __expf(Ss[j * 64 + t] - m);
      Ss[j * 64 + t] = e;
      sum += e;
    }
    float inv = 1.f / sum;
    for (int j = 0; j < SE; ++j) Ss[j * 64 + t] *= inv;
  }
  __syncthreads();
  int d = t % 64;
  int qg = t / 64;
  float acc[16];
#pragma unroll
  for (int m = 0; m < 16; m++) acc[m] = 0.f;
  for (int j = 0; j < SE; ++j) {
    float v = Vs[j * 64 + d];
#pragma unroll
    for (int m = 0; m < 16; m++) acc[m] += Ss[j * 64 + qg * 16 + m] * v;
  }
#pragma unroll
  for (int m = 0; m < 16; m++) {
    size_t o = (size_t)(b * SEQ + s0 + qg * 16 + m) * H + h * 64 + d;
    float v = acc[m];
    short hh = f2bf(v);
    aoh[o] = hh;
    aol[o] = f2bf(v - bf2f(hh));
  }
}

// ---------------------------------------------------------------------------
extern "C" void kernel_launch(void* const* d_in, const int* in_sizes, int n_in,
                              void* d_out, int out_size, void* d_ws,
                              size_t ws_size, hipStream_t stream) {
  const float* hidden = (const float*)d_in[0];
  const float* enc = (const float*)d_in[1];
  const float* W_Q = (const float*)d_in[2];
  const float* W_K = (const float*)d_in[3];
  const float* W_V = (const float*)d_in[4];
  const float* Wq = (const float*)d_in[5];
  const float* Wk = (const float*)d_in[6];
  const float* Wv = (const float*)d_in[7];
  const float* Wo = (const float*)d_in[8];
  const float* bo = (const float*)d_in[9];
  float* out = (float*)d_out;
  float* ws = (float*)d_ws;

  float* Qs = ws + QS_OFF;
  float* Pa = ws + PA_OFF;
  float* Pb = ws + PB_OFF;
  float* WqF = ws + WQF_OFF;
  float* WkF = ws + WKF_OFF;
  float* WvF = ws + WVF_OFF;
  float* qbuf = ws + QBUF_OFF;
  float* kbuf = ws + KBUF_OFF;
  float* vbuf = ws + VBUF_OFF;
  short* HidH = (short*)(ws + HIDH_OFF);
  short* HidL = (short*)(ws + HIDL_OFF);
  short* EncH = (short*)(ws + ENCH_OFF);
  short* EncL = (short*)(ws + ENCL_OFF);
  short* WqTh = (short*)(ws + WQTH_OFF);
  short* WqTl = (short*)(ws + WQTL_OFF);
  short* WkTh = (short*)(ws + WKTH_OFF);
  short* WkTl = (short*)(ws + WKTL_OFF);
  short* WvTh = (short*)(ws + WVTH_OFF);
  short* WvTl = (short*)(ws + WVTL_OFF);
  short* WoTh = (short*)(ws + WOTH_OFF);
  short* WoTl = (short*)(ws + WOTL_OFF);
  short* AOh = HidH;  // overlay: hidden splits dead after q GEMM
  short* AOl = HidL;

  // Cayley via Neumann series folded into the projection weights
  skew_kernel<<<3, 1024, 0, stream>>>(W_Q, W_K, W_V, Qs);
  horner_kernel<<<600, 256, 0, stream>>>(Qs, Qs, Pa);
  horner_kernel<<<600, 256, 0, stream>>>(Qs, Pa, Pb);
  horner_kernel<<<600, 256, 0, stream>>>(Qs, Pb, Pa);
  horner_kernel<<<600, 256, 0, stream>>>(Qs, Pa, Pb);
  horner_kernel<<<600, 256, 0, stream>>>(Qs, Pb, Pa);
  fold_kernel<<<dim3(8, 20, 3), 256, 0, stream>>>(Wq, Wk, Wv, Pa, WqF, WkF,
                                                  WvF);

  // weight transpose + bf16 hi/lo split
  tsplit_kernel<<<dim3(40, 40), 256, 0, stream>>>(WqF, WqTh, WqTl, H, H);
  tsplit_kernel<<<dim3(24, 40), 256, 0, stream>>>(WkF, WkTh, WkTl, CENC, H);
  tsplit_kernel<<<dim3(24, 40), 256, 0, stream>>>(WvF, WvTh, WvTl, CENC, H);
  tsplit_kernel<<<dim3(40, 40), 256, 0, stream>>>(Wo, WoTh, WoTl, H, H);

  // activation splits
  split_kernel<<<2048, 256, 0, stream>>>(hidden, HidH, HidL,
                                         (BATCH * SEQ * H) / 4);
  split_kernel<<<512, 256, 0, stream>>>(enc, EncH, EncL,
                                        (BATCH * SE * CENC) / 4);

  // projections (bf16x3 split MFMA)
  gemm_mfma<<<dim3(128, 10), 256, 0, stream>>>(HidH, HidL, WqTh, WqTl, qbuf,
                                               BATCH * SEQ, H, H, nullptr);
  gemm_mfma<<<dim3(10, 10), 256, 0, stream>>>(EncH, EncL, WkTh, WkTl, kbuf,
                                              BATCH * SE, H, CENC, nullptr);
  gemm_mfma<<<dim3(10, 10), 256, 0, stream>>>(EncH, EncL, WvTh, WvTl, vbuf,
                                              BATCH * SE, H, CENC, nullptr);

  // attention (writes bf16 hi/lo, overlaid on hidden-split buffers)
  attn_kernel<<<BATCH * HEADS * (SEQ / 64), 256, 0, stream>>>(qbuf, kbuf, vbuf,
                                                              AOh, AOl);

  // output projection + bias
  gemm_mfma<<<dim3(128, 10), 256, 0, stream>>>(AOh, AOl, WoTh, WoTl, out,
                                               BATCH * SEQ, H, H, bo);
}